// Round 2
// baseline (363.749 us; speedup 1.0000x reference)
//
#include <hip/hip_runtime.h>
#include <hip/hip_cooperative_groups.h>
#include <stdint.h>

namespace cg = cooperative_groups;

#define T_DIM 8192
#define B_DIM 4096
#define NSEG 16                 // segments along T (512 rows each)
#define CTILE 256               // columns per block
#define NEG_SLOPE 0.01f

// One fused cooperative kernel. Block = (column-tile, segment).
// Phase 1: pack this tile's 0/1 input into per-thread register bit-words
//          (32 rows x 4 cols per thread), LDS-reduce per-column popcounts,
//          wave 0 publishes the segment's column totals to global.
// grid.sync() (cooperative: 256 blocks x 1024 thr = 1 block/CU, co-resident;
//          the sync's device-scope fence handles cross-XCD L2 visibility).
// Phase 2: base = sum of preceding segments' totals (<=15 int4 loads, L2-hot)
//          + preceding word-rows' popcounts from LDS (still live across sync),
//          then emit leaky_relu(fma(count, d1-d0, (t+1)*d0)) as float4.
__global__ __launch_bounds__(1024, 1) void fused_counter(
        const int* __restrict__ in,
        const float* __restrict__ delta,
        float* __restrict__ out,
        int* __restrict__ segTotal) {
    const int c4  = threadIdx.x & 63;          // column-quad lane
    const int rc  = threadIdx.x >> 6;          // word-row within segment, 0..15
    const int col0 = blockIdx.x * CTILE + c4 * 4;
    const int seg = blockIdx.y;
    const int wordrow = seg * 16 + rc;         // global word row 0..255
    const int row0 = wordrow * 32;

    // ---- Phase 1: pack bits into registers ----
    const int4* __restrict__ inv = (const int4*)in;
    uint32_t b0 = 0, b1 = 0, b2 = 0, b3 = 0;
#pragma unroll
    for (int r = 0; r < 32; ++r) {
        int4 v = inv[((size_t)(row0 + r) * B_DIM + col0) >> 2];
        b0 |= ((uint32_t)v.x & 1u) << r;
        b1 |= ((uint32_t)v.y & 1u) << r;
        b2 |= ((uint32_t)v.z & 1u) << r;
        b3 |= ((uint32_t)v.w & 1u) << r;
    }

    __shared__ int4 lds[16 * 64];
    lds[rc * 64 + c4] = make_int4(__popc(b0), __popc(b1), __popc(b2), __popc(b3));
    __syncthreads();

    if (rc == 0) {
        int4 s = make_int4(0, 0, 0, 0);
#pragma unroll
        for (int i = 0; i < 16; ++i) {
            int4 v = lds[i * 64 + c4];
            s.x += v.x; s.y += v.y; s.z += v.z; s.w += v.w;
        }
        ((int4*)segTotal)[((size_t)seg * B_DIM + col0) >> 2] = s;
    }

    // ---- grid-wide barrier (includes device-scope memory fence) ----
    cg::this_grid().sync();

    // ---- Phase 2: base counts ----
    int c0 = 0, c1 = 0, c2 = 0, c3 = 0;
    for (int s = 0; s < seg; ++s) {
        int4 v = ((const int4*)segTotal)[((size_t)s * B_DIM + col0) >> 2];
        c0 += v.x; c1 += v.y; c2 += v.z; c3 += v.w;
    }
    for (int i = 0; i < rc; ++i) {          // rc is wave-uniform
        int4 v = lds[i * 64 + c4];
        c0 += v.x; c1 += v.y; c2 += v.z; c3 += v.w;
    }

    const float d0 = delta[0];
    const float dd = delta[1] - d0;

    // ---- emit ----
    float4* __restrict__ outv = (float4*)out;
#pragma unroll
    for (int r = 0; r < 32; ++r) {
        const int t = row0 + r;
        const float tp = (float)(t + 1) * d0;
        c0 += (int)((b0 >> r) & 1u);
        c1 += (int)((b1 >> r) & 1u);
        c2 += (int)((b2 >> r) & 1u);
        c3 += (int)((b3 >> r) & 1u);
        float4 o;
        o.x = fmaf((float)c0, dd, tp);
        o.y = fmaf((float)c1, dd, tp);
        o.z = fmaf((float)c2, dd, tp);
        o.w = fmaf((float)c3, dd, tp);
        o.x = (o.x >= 0.0f) ? o.x : NEG_SLOPE * o.x;
        o.y = (o.y >= 0.0f) ? o.y : NEG_SLOPE * o.y;
        o.z = (o.z >= 0.0f) ? o.z : NEG_SLOPE * o.z;
        o.w = (o.w >= 0.0f) ? o.w : NEG_SLOPE * o.w;
        outv[((size_t)t * B_DIM + col0) >> 2] = o;
    }
}

extern "C" void kernel_launch(void* const* d_in, const int* in_sizes, int n_in,
                              void* d_out, int out_size, void* d_ws, size_t ws_size,
                              hipStream_t stream) {
    const int*   in    = (const int*)d_in[0];
    const float* delta = (const float*)d_in[1];
    float*       out   = (float*)d_out;
    int*         segTotal = (int*)d_ws;   // NSEG * B_DIM * 4 = 256 KiB

    dim3 grid(B_DIM / CTILE, NSEG);   // (16, 16) = 256 blocks
    dim3 block(1024);

    void* args[] = { (void*)&in, (void*)&delta, (void*)&out, (void*)&segTotal };
    hipLaunchCooperativeKernel((void*)fused_counter, grid, block, args, 0, stream);
}

// Round 3
// 322.286 us; speedup vs baseline: 1.1287x; 1.1287x over previous
//
#include <hip/hip_runtime.h>
#include <stdint.h>

#define T_DIM 8192
#define B_DIM 4096
#define NSEG 16                 // segments along T (512 rows each)
#define CTILE 256               // columns per block
#define NEG_SLOPE 0.01f
#define READY_MAX 1024u         // published values are count+1 in [1,513];
                                // 0xAAAAAAAA poison (and any garbage > 1024) = not ready

// Single kernel, decoupled lookback (no grid barrier, no bits round-trip).
// Block = (column-tile x, segment y). Dispatch order: x fastest, so all
// predecessors of (x, seg) have smaller linear IDs. 256 blocks of 1024 thr,
// VGPR<=64 & LDS 17KB -> 2 blocks/CU capacity; all co-resident.
__global__ __launch_bounds__(1024, 1) void counter_lookback(
        const int* __restrict__ in,
        const float* __restrict__ delta,
        float* __restrict__ out,
        unsigned* __restrict__ segTotal) {
    const int c4  = threadIdx.x & 63;          // column-quad lane
    const int rc  = threadIdx.x >> 6;          // word-row within segment, 0..15
    const int col0 = blockIdx.x * CTILE + c4 * 4;
    const int seg = blockIdx.y;
    const int wordrow = seg * 16 + rc;
    const int row0 = wordrow * 32;

    // ---- Phase 1: pack 32 rows x 4 cols of 0/1 input into register bit-words
    const int4* __restrict__ inv = (const int4*)in;
    uint32_t b0 = 0, b1 = 0, b2 = 0, b3 = 0;
#pragma unroll
    for (int r = 0; r < 32; ++r) {
        int4 v = inv[((size_t)(row0 + r) * B_DIM + col0) >> 2];
        b0 |= ((uint32_t)v.x & 1u) << r;
        b1 |= ((uint32_t)v.y & 1u) << r;
        b2 |= ((uint32_t)v.z & 1u) << r;
        b3 |= ((uint32_t)v.w & 1u) << r;
    }

    __shared__ int4 lds[16 * 64];      // per word-row, per col-quad popcounts
    __shared__ int4 ldsBase[64];       // lookback result per col-quad
    lds[rc * 64 + c4] = make_int4(__popc(b0), __popc(b1), __popc(b2), __popc(b3));
    __syncthreads();

    // ---- Wave 0: publish this segment's totals, then lookback predecessors
    if (rc == 0) {
        int4 s = make_int4(0, 0, 0, 0);
#pragma unroll
        for (int i = 0; i < 16; ++i) {
            int4 v = lds[i * 64 + c4];
            s.x += v.x; s.y += v.y; s.z += v.z; s.w += v.w;
        }
        unsigned* p = segTotal + (size_t)seg * B_DIM + col0;
        __hip_atomic_store(p + 0, (unsigned)(s.x + 1), __ATOMIC_RELAXED, __HIP_MEMORY_SCOPE_AGENT);
        __hip_atomic_store(p + 1, (unsigned)(s.y + 1), __ATOMIC_RELAXED, __HIP_MEMORY_SCOPE_AGENT);
        __hip_atomic_store(p + 2, (unsigned)(s.z + 1), __ATOMIC_RELAXED, __HIP_MEMORY_SCOPE_AGENT);
        __hip_atomic_store(p + 3, (unsigned)(s.w + 1), __ATOMIC_RELAXED, __HIP_MEMORY_SCOPE_AGENT);

        int c0 = 0, c1 = 0, c2 = 0, c3 = 0;
        for (int sg = 0; sg < seg; ++sg) {
            const unsigned* q = segTotal + (size_t)sg * B_DIM + col0;
            unsigned x, y, z, w;
            do {   // value-carrying flags: poison/garbage reads > READY_MAX
                x = __hip_atomic_load(q + 0, __ATOMIC_RELAXED, __HIP_MEMORY_SCOPE_AGENT);
                y = __hip_atomic_load(q + 1, __ATOMIC_RELAXED, __HIP_MEMORY_SCOPE_AGENT);
                z = __hip_atomic_load(q + 2, __ATOMIC_RELAXED, __HIP_MEMORY_SCOPE_AGENT);
                w = __hip_atomic_load(q + 3, __ATOMIC_RELAXED, __HIP_MEMORY_SCOPE_AGENT);
            } while (x > READY_MAX || y > READY_MAX || z > READY_MAX || w > READY_MAX);
            c0 += (int)x - 1; c1 += (int)y - 1; c2 += (int)z - 1; c3 += (int)w - 1;
        }
        ldsBase[c4] = make_int4(c0, c1, c2, c3);
    }
    __syncthreads();

    // ---- Base = lookback result + preceding word-rows within segment
    int4 base = ldsBase[c4];
    int c0 = base.x, c1 = base.y, c2 = base.z, c3 = base.w;
    for (int i = 0; i < rc; ++i) {     // rc is wave-uniform
        int4 v = lds[i * 64 + c4];
        c0 += v.x; c1 += v.y; c2 += v.z; c3 += v.w;
    }

    const float d0 = delta[0];
    const float dd = delta[1] - d0;

    // ---- Emit leaky_relu(fma(count, d1-d0, (t+1)*d0)) as float4
    float4* __restrict__ outv = (float4*)out;
#pragma unroll
    for (int r = 0; r < 32; ++r) {
        const int t = row0 + r;
        const float tp = (float)(t + 1) * d0;
        c0 += (int)((b0 >> r) & 1u);
        c1 += (int)((b1 >> r) & 1u);
        c2 += (int)((b2 >> r) & 1u);
        c3 += (int)((b3 >> r) & 1u);
        float4 o;
        o.x = fmaf((float)c0, dd, tp);
        o.y = fmaf((float)c1, dd, tp);
        o.z = fmaf((float)c2, dd, tp);
        o.w = fmaf((float)c3, dd, tp);
        o.x = (o.x >= 0.0f) ? o.x : NEG_SLOPE * o.x;
        o.y = (o.y >= 0.0f) ? o.y : NEG_SLOPE * o.y;
        o.z = (o.z >= 0.0f) ? o.z : NEG_SLOPE * o.z;
        o.w = (o.w >= 0.0f) ? o.w : NEG_SLOPE * o.w;
        outv[((size_t)t * B_DIM + col0) >> 2] = o;
    }
}

extern "C" void kernel_launch(void* const* d_in, const int* in_sizes, int n_in,
                              void* d_out, int out_size, void* d_ws, size_t ws_size,
                              hipStream_t stream) {
    const int*   in    = (const int*)d_in[0];
    const float* delta = (const float*)d_in[1];
    float*       out   = (float*)d_out;
    unsigned*    segTotal = (unsigned*)d_ws;   // NSEG * B_DIM * 4 = 256 KiB

    // Defensive re-poison of the flag region (first call's ws state is not
    // guaranteed; 0xAA pattern = "not ready"). Async memset is capturable.
    hipMemsetAsync(segTotal, 0xAA, (size_t)NSEG * B_DIM * sizeof(unsigned), stream);

    dim3 grid(B_DIM / CTILE, NSEG);   // (16, 16) = 256 blocks
    dim3 block(1024);
    hipLaunchKernelGGL(counter_lookback, grid, block, 0, stream,
                       in, delta, out, segTotal);
}

// Round 5
// 225.956 us; speedup vs baseline: 1.6098x; 1.4263x over previous
//
#include <hip/hip_runtime.h>
#include <stdint.h>

#define T_DIM 8192
#define B_DIM 4096
#define NSEG 32                 // 32 segments x 256 rows (8 word-rows) each
#define CTILE 256               // columns per block
#define NEG_SLOPE 0.01f

// Native clang vector types: __builtin_nontemporal_* requires these
// (HIP_vector_type wrappers are rejected).
typedef int   ivec4 __attribute__((ext_vector_type(4)));
typedef float fvec4 __attribute__((ext_vector_type(4)));

// Split streaming design (round-1 structure, higher occupancy + nt hints).
// Thread = 16 rows x 4 cols (half a 32-bit word per column). 1024-thr blocks,
// grid (16,32) = 512 blocks = 8192 waves = 32 waves/CU at 2 blocks/CU.

// ---------------------------------------------------------------------------
// KA: stream input (read-once, nt loads), pack bits, publish per-segment
// column totals. Block = one segment x 256 cols.
// ---------------------------------------------------------------------------
__global__ __launch_bounds__(1024, 8) void ka_pack(const int* __restrict__ in,
                                                   uint32_t* __restrict__ bits,
                                                   int* __restrict__ segTotal) {
    const int c4   = threadIdx.x & 63;         // column-quad lane
    const int rr   = threadIdx.x >> 6;         // 0..15: (word-row-local, half)
    const int wl   = rr >> 1;                  // word-row within segment, 0..7
    const int half = rr & 1;                   // 0 = bits 0..15, 1 = bits 16..31
    const int col0 = blockIdx.x * CTILE + c4 * 4;
    const int wordrow = blockIdx.y * 8 + wl;   // global word row, 0..255
    const int row0 = wordrow * 32 + half * 16;

    const ivec4* __restrict__ inv = (const ivec4*)in;
    uint32_t b0 = 0, b1 = 0, b2 = 0, b3 = 0;
#pragma unroll
    for (int r = 0; r < 16; ++r) {
        ivec4 v = __builtin_nontemporal_load(&inv[((size_t)(row0 + r) * B_DIM + col0) >> 2]);
        b0 |= ((uint32_t)v.x & 1u) << r;
        b1 |= ((uint32_t)v.y & 1u) << r;
        b2 |= ((uint32_t)v.z & 1u) << r;
        b3 |= ((uint32_t)v.w & 1u) << r;
    }

    __shared__ uint4 halves[16][64];
    __shared__ int4  cnts[8][64];
    halves[rr][c4] = make_uint4(b0, b1, b2, b3);
    __syncthreads();

    if (half == 0) {
        uint4 lo = halves[rr][c4];
        uint4 hi = halves[rr + 1][c4];
        uint4 w = make_uint4(lo.x | (hi.x << 16), lo.y | (hi.y << 16),
                             lo.z | (hi.z << 16), lo.w | (hi.w << 16));
        ((uint4*)bits)[((size_t)wordrow * B_DIM + col0) >> 2] = w;
        cnts[wl][c4] = make_int4(__popc(w.x), __popc(w.y), __popc(w.z), __popc(w.w));
    }
    __syncthreads();

    if (rr == 0) {  // wave 0: column totals for this segment
        int4 s = make_int4(0, 0, 0, 0);
#pragma unroll
        for (int i = 0; i < 8; ++i) {
            int4 v = cnts[i][c4];
            s.x += v.x; s.y += v.y; s.z += v.z; s.w += v.w;
        }
        ((int4*)segTotal)[((size_t)blockIdx.y * B_DIM + col0) >> 2] = s;
    }
}

// ---------------------------------------------------------------------------
// KB: reload packed bits (4 MB, L2/L3-hot) + segment totals, reconstruct the
// exact prefix count, emit leaky_relu via nt float4 stores (write-once).
// ---------------------------------------------------------------------------
__global__ __launch_bounds__(1024, 8) void kb_emit(const uint32_t* __restrict__ bits,
                                                   const int* __restrict__ segTotal,
                                                   const float* __restrict__ delta,
                                                   float* __restrict__ out) {
    const int c4   = threadIdx.x & 63;
    const int rr   = threadIdx.x >> 6;
    const int wl   = rr >> 1;
    const int half = rr & 1;
    const int col0 = blockIdx.x * CTILE + c4 * 4;
    const int seg  = blockIdx.y;
    const int wordrow = seg * 8 + wl;
    const int row0 = wordrow * 32 + half * 16;

    uint4 w = ((const uint4*)bits)[((size_t)wordrow * B_DIM + col0) >> 2];

    __shared__ int4 cnts[8][64];
    if (half == 0)
        cnts[wl][c4] = make_int4(__popc(w.x), __popc(w.y), __popc(w.z), __popc(w.w));

    // base from preceding segments (same addrs across waves -> L1 broadcast)
    int c0 = 0, c1 = 0, c2 = 0, c3 = 0;
    for (int s = 0; s < seg; ++s) {
        int4 v = ((const int4*)segTotal)[((size_t)s * B_DIM + col0) >> 2];
        c0 += v.x; c1 += v.y; c2 += v.z; c3 += v.w;
    }
    __syncthreads();

    // + preceding word-rows within segment (wl is wave-uniform)
    for (int i = 0; i < wl; ++i) {
        int4 v = cnts[i][c4];
        c0 += v.x; c1 += v.y; c2 += v.z; c3 += v.w;
    }
    // + lower half of own word if this thread handles the upper half
    if (half) {
        c0 += __popc(w.x & 0xFFFFu);
        c1 += __popc(w.y & 0xFFFFu);
        c2 += __popc(w.z & 0xFFFFu);
        c3 += __popc(w.w & 0xFFFFu);
    }

    const float d0 = delta[0];
    const float dd = delta[1] - d0;
    const int sh = half * 16;

    fvec4* __restrict__ outv = (fvec4*)out;
#pragma unroll
    for (int r = 0; r < 16; ++r) {
        const int t = row0 + r;
        const float tp = (float)(t + 1) * d0;
        c0 += (int)((w.x >> (sh + r)) & 1u);
        c1 += (int)((w.y >> (sh + r)) & 1u);
        c2 += (int)((w.z >> (sh + r)) & 1u);
        c3 += (int)((w.w >> (sh + r)) & 1u);
        fvec4 o;
        float ox = fmaf((float)c0, dd, tp);
        float oy = fmaf((float)c1, dd, tp);
        float oz = fmaf((float)c2, dd, tp);
        float ow = fmaf((float)c3, dd, tp);
        o.x = (ox >= 0.0f) ? ox : NEG_SLOPE * ox;
        o.y = (oy >= 0.0f) ? oy : NEG_SLOPE * oy;
        o.z = (oz >= 0.0f) ? oz : NEG_SLOPE * oz;
        o.w = (ow >= 0.0f) ? ow : NEG_SLOPE * ow;
        __builtin_nontemporal_store(o, &outv[((size_t)t * B_DIM + col0) >> 2]);
    }
}

extern "C" void kernel_launch(void* const* d_in, const int* in_sizes, int n_in,
                              void* d_out, int out_size, void* d_ws, size_t ws_size,
                              hipStream_t stream) {
    const int*   in    = (const int*)d_in[0];
    const float* delta = (const float*)d_in[1];
    float*       out   = (float*)d_out;

    uint32_t* bits     = (uint32_t*)d_ws;                                    // 4 MiB
    int*      segTotal = (int*)((char*)d_ws + (size_t)(T_DIM / 32) * B_DIM * 4);

    dim3 grid(B_DIM / CTILE, NSEG);   // (16, 32) = 512 blocks
    dim3 block(1024);

    hipLaunchKernelGGL(ka_pack, grid, block, 0, stream, in, bits, segTotal);
    hipLaunchKernelGGL(kb_emit, grid, block, 0, stream, bits, segTotal, delta, out);
}